// Round 1
// baseline (1573.129 us; speedup 1.0000x reference)
//
#include <hip/hip_runtime.h>
#include <hip/hip_bf16.h>

// Problem constants (from reference)
#define BT 4096
#define HD 2048
#define VD 32000
#define IGNORE_IDX (-100)

// Tiling
#define BM 128
#define BN 128
#define BKT 32
#define NRB (BT / BM)   // 32 row blocks
#define NCB (VD / BN)   // 250 col (vocab) blocks

using short8 = __attribute__((ext_vector_type(8))) short;
using f32x4  = __attribute__((ext_vector_type(4))) float;

__device__ __forceinline__ unsigned short f2bf(float f) {
  // round-to-nearest-even fp32 -> bf16
  unsigned u = __float_as_uint(f);
  u = (u + 0x7fffu + ((u >> 16) & 1u)) >> 16;
  return (unsigned short)u;
}

// ---------------------------------------------------------------------------
// Detect whether target buffer is int64 or int32.
// Reads first 2048 elements as int64 (16KB -- safe either way). If data is
// really int32, pairs combine into huge values -> flagged bad.
// badcnt == 0  =>  int64 layout.
// ---------------------------------------------------------------------------
__global__ void detect_tgt_kernel(const long long* __restrict__ t64,
                                  int* __restrict__ badcnt) {
  int i = blockIdx.x * blockDim.x + threadIdx.x;  // 2048 threads
  long long v = t64[i];
  bool valid = (v == (long long)IGNORE_IDX) || (v >= 0 && v < (long long)VD);
  if (!valid) atomicAdd(badcnt, 1);
}

// ---------------------------------------------------------------------------
// Fused GEMM (x @ W^T) + per-(rowblock,colblock) partial sum(exp(logit))
// + picked target logit.  bf16 MFMA with on-the-fly fp32->bf16 conversion.
// ---------------------------------------------------------------------------
__global__ __launch_bounds__(256) void gemm_lse_kernel(
    const float* __restrict__ x, const float* __restrict__ w,
    const void* __restrict__ tgt, const int* __restrict__ badcnt,
    float* __restrict__ partialS, float* __restrict__ picked) {
  __shared__ unsigned short As[BM][BKT];  // 8 KB
  __shared__ unsigned short Bs[BN][BKT];  // 8 KB

  const int bid  = blockIdx.x;
  const int rb   = bid % NRB;   // rowblock fast: concurrent blocks share W strip
  const int cb   = bid / NRB;
  const int row0 = rb * BM;
  const int col0 = cb * BN;
  const int t    = threadIdx.x;
  const int lane = t & 63;
  const int wave = t >> 6;
  const int wr   = wave >> 1;   // wave row (0..1), owns 64 rows
  const int wc   = wave & 1;    // wave col (0..1), owns 64 cols

  // staging: thread t loads float4 at (tile row = t/8 + j*32, col = (t%8)*4)
  const int srow = t >> 3;        // 0..31
  const int scol = (t & 7) * 4;   // 0,4,...,28

  const float* xA = x + (size_t)row0 * HD;
  const float* wB = w + (size_t)col0 * HD;

  f32x4 acc[4][4];
#pragma unroll
  for (int i = 0; i < 4; i++)
#pragma unroll
    for (int j = 0; j < 4; j++)
#pragma unroll
      for (int q = 0; q < 4; q++) acc[i][j][q] = 0.f;

  float4 ra[4], rbv[4];

#define STAGE_LOAD(k0)                                                        \
  {                                                                           \
    _Pragma("unroll") for (int j = 0; j < 4; j++) {                           \
      ra[j]  = *(const float4*)(xA + (size_t)(srow + j * 32) * HD + (k0) + scol); \
      rbv[j] = *(const float4*)(wB + (size_t)(srow + j * 32) * HD + (k0) + scol); \
    }                                                                         \
  }

#define STAGE_WRITE()                                                         \
  {                                                                           \
    _Pragma("unroll") for (int j = 0; j < 4; j++) {                           \
      ushort4 pa = make_ushort4(f2bf(ra[j].x), f2bf(ra[j].y), f2bf(ra[j].z),  \
                                f2bf(ra[j].w));                               \
      ushort4 pb = make_ushort4(f2bf(rbv[j].x), f2bf(rbv[j].y),               \
                                f2bf(rbv[j].z), f2bf(rbv[j].w));              \
      *(ushort4*)&As[srow + j * 32][scol] = pa;                               \
      *(ushort4*)&Bs[srow + j * 32][scol] = pb;                               \
    }                                                                         \
  }

  const int ks = (lane >> 4) * 8;  // k-slice start within BK=32
  const int fr = lane & 15;        // fragment row/col index

  STAGE_LOAD(0);
  STAGE_WRITE();
  __syncthreads();

  for (int k0 = 0; k0 < HD; k0 += BKT) {
    const bool notlast = (k0 + BKT < HD);
    if (notlast) STAGE_LOAD(k0 + BKT);  // prefetch next tile into regs

    short8 af[4], bfv[4];
#pragma unroll
    for (int i = 0; i < 4; i++) {
      af[i]  = *(const short8*)&As[wr * 64 + i * 16 + fr][ks];
      bfv[i] = *(const short8*)&Bs[wc * 64 + i * 16 + fr][ks];
    }
#pragma unroll
    for (int i = 0; i < 4; i++)
#pragma unroll
      for (int j = 0; j < 4; j++)
        acc[i][j] =
            __builtin_amdgcn_mfma_f32_16x16x32_bf16(af[i], bfv[j], acc[i][j], 0, 0, 0);

    __syncthreads();  // everyone done reading LDS tile
    if (notlast) STAGE_WRITE();
    __syncthreads();  // LDS tile (k0+BK) ready
  }

  // ---- epilogue: per-row sum(exp) over this block's 128 cols --------------
  // acc layout (verified m89): col = lane&15, row = (lane>>4)*4 + reg
  float rsum[16];  // [mi*4 + r]
#pragma unroll
  for (int mi = 0; mi < 4; mi++) {
#pragma unroll
    for (int r = 0; r < 4; r++) {
      float s = 0.f;
#pragma unroll
      for (int nj = 0; nj < 4; nj++) s += expf(acc[mi][nj][r]);
      rsum[mi * 4 + r] = s;
    }
  }
  // reduce across the 16 lanes (same lane>>4 group) holding different cols
#pragma unroll
  for (int m = 1; m < 16; m <<= 1) {
#pragma unroll
    for (int q = 0; q < 16; q++) rsum[q] += __shfl_xor(rsum[q], m, 64);
  }

  __syncthreads();  // safe to reuse As as reduction buffer
  float* red = (float*)&As[0][0];  // [4 waves][64 rows]
  if (fr == 0) {
#pragma unroll
    for (int mi = 0; mi < 4; mi++)
#pragma unroll
      for (int r = 0; r < 4; r++)
        red[wave * 64 + mi * 16 + (lane >> 4) * 4 + r] = rsum[mi * 4 + r];
  }
  __syncthreads();

  if (t < BM) {
    int rl   = t;
    int wrow = rl >> 6;
    float S  = red[(wrow * 2 + 0) * 64 + (rl & 63)] +
               red[(wrow * 2 + 1) * 64 + (rl & 63)];
    partialS[(size_t)cb * BT + row0 + rl] = S;
  }

  // ---- picked target logit (exactly one writer per row over all blocks) ---
  const bool is64 = (*badcnt == 0);
#pragma unroll
  for (int mi = 0; mi < 4; mi++) {
#pragma unroll
    for (int r = 0; r < 4; r++) {
      int grow = row0 + wr * 64 + mi * 16 + ((lane >> 4) << 2) + r;
      long long tv = is64 ? ((const long long*)tgt)[grow]
                          : (long long)((const int*)tgt)[grow];
#pragma unroll
      for (int nj = 0; nj < 4; nj++) {
        int gcol = col0 + wc * 64 + nj * 16 + fr;
        if (tv == (long long)gcol) picked[grow] = acc[mi][nj][r];
      }
    }
  }
#undef STAGE_LOAD
#undef STAGE_WRITE
}

// ---------------------------------------------------------------------------
// Per-row: S = sum of 250 partials; nll = log(S) - picked
// ---------------------------------------------------------------------------
__global__ void reduce_rows_kernel(const float* __restrict__ partialS,
                                   const float* __restrict__ picked,
                                   float* __restrict__ nll) {
  int r = blockIdx.x * blockDim.x + threadIdx.x;
  if (r >= BT) return;
  float S = 0.f;
  for (int cb = 0; cb < NCB; cb++) S += partialS[(size_t)cb * BT + r];
  nll[r] = logf(S) - picked[r];
}

// ---------------------------------------------------------------------------
// Final: loss = sum(nll) / n_non_ignore   (deterministic single-block reduce)
// ---------------------------------------------------------------------------
__global__ void reduce_final_kernel(const float* __restrict__ nll,
                                    const void* __restrict__ tgt,
                                    const int* __restrict__ badcnt,
                                    float* __restrict__ out) {
  __shared__ float ssum[256];
  __shared__ int   scnt[256];
  int t = threadIdx.x;
  const bool is64 = (*badcnt == 0);
  float s = 0.f;
  int   c = 0;
  for (int r = t; r < BT; r += 256) {
    s += nll[r];
    long long tv = is64 ? ((const long long*)tgt)[r]
                        : (long long)((const int*)tgt)[r];
    c += (tv != (long long)IGNORE_IDX) ? 1 : 0;
  }
  ssum[t] = s;
  scnt[t] = c;
  __syncthreads();
  for (int o = 128; o > 0; o >>= 1) {
    if (t < o) {
      ssum[t] += ssum[t + o];
      scnt[t] += scnt[t + o];
    }
    __syncthreads();
  }
  if (t == 0) out[0] = ssum[0] / (float)scnt[0];
}

// ---------------------------------------------------------------------------
extern "C" void kernel_launch(void* const* d_in, const int* in_sizes, int n_in,
                              void* d_out, int out_size, void* d_ws,
                              size_t ws_size, hipStream_t stream) {
  const float* x   = (const float*)d_in[0];
  const float* w   = (const float*)d_in[1];
  const void*  tgt = d_in[2];
  float*       out = (float*)d_out;

  char* ws = (char*)d_ws;
  // ws layout:
  //   [0, NCB*BT*4)                       : partialS  (4,096,000 B)
  //   [offA, offA+16)                     : badcnt flag (+pad)
  //   [offA+16, offA+16+BT*4)             : picked
  //   [offA+16+BT*4, offA+16+2*BT*4)      : nll
  const size_t offA    = (size_t)NCB * BT * sizeof(float);
  float* partialS      = (float*)ws;
  int*   badcnt        = (int*)(ws + offA);
  float* picked        = (float*)(ws + offA + 16);
  float* nll           = (float*)(ws + offA + 16 + (size_t)BT * 4);

  // zero flag + picked (picked default 0 == reference's masked value)
  hipMemsetAsync(ws + offA, 0, 16 + (size_t)BT * 4, stream);

  detect_tgt_kernel<<<8, 256, 0, stream>>>((const long long*)tgt, badcnt);

  gemm_lse_kernel<<<NRB * NCB, 256, 0, stream>>>(x, w, tgt, badcnt, partialS,
                                                 picked);

  reduce_rows_kernel<<<BT / 256, 256, 0, stream>>>(partialS, picked, nll);

  reduce_final_kernel<<<1, 256, 0, stream>>>(nll, tgt, badcnt, out);
}

// Round 2
// 1314.979 us; speedup vs baseline: 1.1963x; 1.1963x over previous
//
#include <hip/hip_runtime.h>
#include <hip/hip_bf16.h>

// Problem constants (from reference)
#define BT 4096
#define HD 2048
#define VD 32000
#define IGNORE_IDX (-100)

// Tiling
#define BM 128
#define BN 128
#define BKT 32   // fp32-path K tile (fallback)
#define BKG 32   // bf16-path K tile
#define NRB (BT / BM)   // 32 row blocks
#define NCB (VD / BN)   // 250 col (vocab) blocks

using short8 = __attribute__((ext_vector_type(8))) short;
using f32x4  = __attribute__((ext_vector_type(4))) float;

__device__ __forceinline__ unsigned short f2bf(float f) {
  // round-to-nearest-even fp32 -> bf16
  unsigned u = __float_as_uint(f);
  u = (u + 0x7fffu + ((u >> 16) & 1u)) >> 16;
  return (unsigned short)u;
}

__device__ __forceinline__ void gload_lds16(const unsigned short* g,
                                            unsigned short* l) {
  // async global->LDS, 16B per lane; LDS dest is wave-uniform base + lane*16
  __builtin_amdgcn_global_load_lds(
      (const __attribute__((address_space(1))) void*)g,
      (__attribute__((address_space(3))) void*)l, 16, 0, 0);
}

// ---------------------------------------------------------------------------
// Detect whether target buffer is int64 or int32 (reads 16KB, safe either way)
// ---------------------------------------------------------------------------
__global__ void detect_tgt_kernel(const long long* __restrict__ t64,
                                  int* __restrict__ badcnt) {
  int i = blockIdx.x * blockDim.x + threadIdx.x;  // 2048 threads
  long long v = t64[i];
  bool valid = (v == (long long)IGNORE_IDX) || (v >= 0 && v < (long long)VD);
  if (!valid) atomicAdd(badcnt, 1);
}

// ---------------------------------------------------------------------------
// fp32 -> bf16 bulk convert (vectorized: 8 floats in, short8 out per iter)
// ---------------------------------------------------------------------------
__global__ void cvt_bf16_kernel(const float* __restrict__ in,
                                unsigned short* __restrict__ out, int n8) {
  int idx = blockIdx.x * blockDim.x + threadIdx.x;
  int stride = gridDim.x * blockDim.x;
  for (int i = idx; i < n8; i += stride) {
    float4 a = ((const float4*)in)[(size_t)2 * i];
    float4 b = ((const float4*)in)[(size_t)2 * i + 1];
    short8 o;
    o[0] = (short)f2bf(a.x);
    o[1] = (short)f2bf(a.y);
    o[2] = (short)f2bf(a.z);
    o[3] = (short)f2bf(a.w);
    o[4] = (short)f2bf(b.x);
    o[5] = (short)f2bf(b.y);
    o[6] = (short)f2bf(b.z);
    o[7] = (short)f2bf(b.w);
    ((short8*)out)[i] = o;
  }
}

// ---------------------------------------------------------------------------
// FAST PATH: bf16 GEMM (x @ W^T) via global_load_lds staging (m97 structure)
// + per-(rowblock,colblock) partial sum(exp(logit)) + picked target logit.
// ---------------------------------------------------------------------------
__global__ __launch_bounds__(256) void gemm_lse_bf16_kernel(
    const unsigned short* __restrict__ xbf,
    const unsigned short* __restrict__ wbf, const void* __restrict__ tgt,
    const int* __restrict__ badcnt, float* __restrict__ partialS,
    float* __restrict__ picked) {
  __shared__ unsigned short As[BM][BKG];  // 8 KB
  __shared__ unsigned short Bs[BN][BKG];  // 8 KB

  // bijective XCD swizzle (nwg=8000, 8000%8==0), then rowblock-fast decompose
  // so the 32 blocks sharing one W panel are consecutive on one XCD's L2.
  const int bid = blockIdx.x;
  const int cpx = (NRB * NCB) >> 3;  // 1000
  const int swz = (bid & 7) * cpx + (bid >> 3);
  const int rb  = swz % NRB;
  const int cb  = swz / NRB;
  const int row0 = rb * BM;
  const int col0 = cb * BN;

  const int t    = threadIdx.x;
  const int lane = t & 63;
  const int wave = t >> 6;
  const int wr   = wave >> 1;  // wave row (0..1): 64 output rows
  const int wc   = wave & 1;   // wave col (0..1): 64 output cols

  // staging geometry: each wave stages 2KB of A + 2KB of B per K-step
  // (2 issues each); lane l covers row = base + l/4, col8 = (l&3)*8
  const int srow = lane >> 2;       // 0..15
  const int scol = (lane & 3) * 8;  // 0,8,16,24

  const unsigned short* xA = xbf + (size_t)row0 * HD;
  const unsigned short* wB = wbf + (size_t)col0 * HD;

#define STAGE(k0)                                                             \
  {                                                                           \
    _Pragma("unroll") for (int i = 0; i < 2; i++) {                           \
      gload_lds16(xA + (size_t)(wave * 32 + i * 16 + srow) * HD + (k0) + scol,\
                  &As[wave * 32 + i * 16][0]);                                \
      gload_lds16(wB + (size_t)(wave * 32 + i * 16 + srow) * HD + (k0) + scol,\
                  &Bs[wave * 32 + i * 16][0]);                                \
    }                                                                         \
  }

  f32x4 acc[4][4];
#pragma unroll
  for (int i = 0; i < 4; i++)
#pragma unroll
    for (int j = 0; j < 4; j++)
#pragma unroll
      for (int q = 0; q < 4; q++) acc[i][j][q] = 0.f;

  const int ks = (lane >> 4) * 8;  // k-slice start within BK=32
  const int fr = lane & 15;        // fragment row/col index

  STAGE(0);
  __syncthreads();

  for (int k0 = 0; k0 < HD; k0 += BKG) {
    short8 af[4], bfv[4];
#pragma unroll
    for (int i = 0; i < 4; i++) {
      af[i]  = *(const short8*)&As[wr * 64 + i * 16 + fr][ks];
      bfv[i] = *(const short8*)&Bs[wc * 64 + i * 16 + fr][ks];
    }
    __syncthreads();  // frag reads drained; LDS reusable
    if (k0 + BKG < HD) STAGE(k0 + BKG);  // async loads fly over the MFMAs
#pragma unroll
    for (int i = 0; i < 4; i++)
#pragma unroll
      for (int j = 0; j < 4; j++)
        acc[i][j] = __builtin_amdgcn_mfma_f32_16x16x32_bf16(af[i], bfv[j],
                                                            acc[i][j], 0, 0, 0);
    __syncthreads();  // vmcnt drained at barrier: next tile resident
  }
#undef STAGE

  // ---- epilogue: per-row sum(exp) over this block's 128 cols --------------
  // acc layout (verified): col = lane&15, row = (lane>>4)*4 + reg
  float rsum[16];  // [mi*4 + r]
#pragma unroll
  for (int mi = 0; mi < 4; mi++) {
#pragma unroll
    for (int r = 0; r < 4; r++) {
      float s = 0.f;
#pragma unroll
      for (int nj = 0; nj < 4; nj++) s += expf(acc[mi][nj][r]);
      rsum[mi * 4 + r] = s;
    }
  }
#pragma unroll
  for (int m = 1; m < 16; m <<= 1) {
#pragma unroll
    for (int q = 0; q < 16; q++) rsum[q] += __shfl_xor(rsum[q], m, 64);
  }

  __syncthreads();  // reuse As as reduction buffer
  float* red = (float*)&As[0][0];  // [4 waves][64 rows] floats (1KB, fits 8KB)
  if (fr == 0) {
#pragma unroll
    for (int mi = 0; mi < 4; mi++)
#pragma unroll
      for (int r = 0; r < 4; r++)
        red[wave * 64 + mi * 16 + (lane >> 4) * 4 + r] = rsum[mi * 4 + r];
  }
  __syncthreads();

  if (t < BM) {
    int rl   = t;
    int wrow = rl >> 6;
    float S  = red[(wrow * 2 + 0) * 64 + (rl & 63)] +
               red[(wrow * 2 + 1) * 64 + (rl & 63)];
    partialS[(size_t)cb * BT + row0 + rl] = S;
  }

  // ---- picked target logit (exactly one writer per row over all blocks) ---
  const bool is64 = (*badcnt == 0);
#pragma unroll
  for (int mi = 0; mi < 4; mi++) {
#pragma unroll
    for (int r = 0; r < 4; r++) {
      int grow = row0 + wr * 64 + mi * 16 + ((lane >> 4) << 2) + r;
      long long tv = is64 ? ((const long long*)tgt)[grow]
                          : (long long)((const int*)tgt)[grow];
#pragma unroll
      for (int nj = 0; nj < 4; nj++) {
        int gcol = col0 + wc * 64 + nj * 16 + fr;
        if (tv == (long long)gcol) picked[grow] = acc[mi][nj][r];
      }
    }
  }
}

// ---------------------------------------------------------------------------
// FALLBACK PATH (ws too small): fp32 inputs with on-the-fly cvt (round-1 code)
// ---------------------------------------------------------------------------
__global__ __launch_bounds__(256) void gemm_lse_kernel(
    const float* __restrict__ x, const float* __restrict__ w,
    const void* __restrict__ tgt, const int* __restrict__ badcnt,
    float* __restrict__ partialS, float* __restrict__ picked) {
  __shared__ unsigned short As[BM][BKT];
  __shared__ unsigned short Bs[BN][BKT];

  const int bid  = blockIdx.x;
  const int rb   = bid % NRB;
  const int cb   = bid / NRB;
  const int row0 = rb * BM;
  const int col0 = cb * BN;
  const int t    = threadIdx.x;
  const int lane = t & 63;
  const int wave = t >> 6;
  const int wr   = wave >> 1;
  const int wc   = wave & 1;

  const int srow = t >> 3;
  const int scol = (t & 7) * 4;

  const float* xA = x + (size_t)row0 * HD;
  const float* wB = w + (size_t)col0 * HD;

  f32x4 acc[4][4];
#pragma unroll
  for (int i = 0; i < 4; i++)
#pragma unroll
    for (int j = 0; j < 4; j++)
#pragma unroll
      for (int q = 0; q < 4; q++) acc[i][j][q] = 0.f;

  float4 ra[4], rbv[4];

#define STAGE_LOAD(k0)                                                        \
  {                                                                           \
    _Pragma("unroll") for (int j = 0; j < 4; j++) {                           \
      ra[j]  = *(const float4*)(xA + (size_t)(srow + j * 32) * HD + (k0) + scol); \
      rbv[j] = *(const float4*)(wB + (size_t)(srow + j * 32) * HD + (k0) + scol); \
    }                                                                         \
  }
#define STAGE_WRITE()                                                         \
  {                                                                           \
    _Pragma("unroll") for (int j = 0; j < 4; j++) {                           \
      ushort4 pa = make_ushort4(f2bf(ra[j].x), f2bf(ra[j].y), f2bf(ra[j].z),  \
                                f2bf(ra[j].w));                               \
      ushort4 pb = make_ushort4(f2bf(rbv[j].x), f2bf(rbv[j].y),               \
                                f2bf(rbv[j].z), f2bf(rbv[j].w));              \
      *(ushort4*)&As[srow + j * 32][scol] = pa;                               \
      *(ushort4*)&Bs[srow + j * 32][scol] = pb;                               \
    }                                                                         \
  }

  const int ks = (lane >> 4) * 8;
  const int fr = lane & 15;

  STAGE_LOAD(0);
  STAGE_WRITE();
  __syncthreads();

  for (int k0 = 0; k0 < HD; k0 += BKT) {
    const bool notlast = (k0 + BKT < HD);
    if (notlast) STAGE_LOAD(k0 + BKT);

    short8 af[4], bfv[4];
#pragma unroll
    for (int i = 0; i < 4; i++) {
      af[i]  = *(const short8*)&As[wr * 64 + i * 16 + fr][ks];
      bfv[i] = *(const short8*)&Bs[wc * 64 + i * 16 + fr][ks];
    }
#pragma unroll
    for (int i = 0; i < 4; i++)
#pragma unroll
      for (int j = 0; j < 4; j++)
        acc[i][j] =
            __builtin_amdgcn_mfma_f32_16x16x32_bf16(af[i], bfv[j], acc[i][j], 0, 0, 0);

    __syncthreads();
    if (notlast) STAGE_WRITE();
    __syncthreads();
  }
#undef STAGE_LOAD
#undef STAGE_WRITE

  float rsum[16];
#pragma unroll
  for (int mi = 0; mi < 4; mi++) {
#pragma unroll
    for (int r = 0; r < 4; r++) {
      float s = 0.f;
#pragma unroll
      for (int nj = 0; nj < 4; nj++) s += expf(acc[mi][nj][r]);
      rsum[mi * 4 + r] = s;
    }
  }
#pragma unroll
  for (int m = 1; m < 16; m <<= 1) {
#pragma unroll
    for (int q = 0; q < 16; q++) rsum[q] += __shfl_xor(rsum[q], m, 64);
  }

  __syncthreads();
  float* red = (float*)&As[0][0];
  if (fr == 0) {
#pragma unroll
    for (int mi = 0; mi < 4; mi++)
#pragma unroll
      for (int r = 0; r < 4; r++)
        red[wave * 64 + mi * 16 + (lane >> 4) * 4 + r] = rsum[mi * 4 + r];
  }
  __syncthreads();

  if (t < BM) {
    int rl   = t;
    int wrow = rl >> 6;
    float S  = red[(wrow * 2 + 0) * 64 + (rl & 63)] +
               red[(wrow * 2 + 1) * 64 + (rl & 63)];
    partialS[(size_t)cb * BT + row0 + rl] = S;
  }

  const bool is64 = (*badcnt == 0);
#pragma unroll
  for (int mi = 0; mi < 4; mi++) {
#pragma unroll
    for (int r = 0; r < 4; r++) {
      int grow = row0 + wr * 64 + mi * 16 + ((lane >> 4) << 2) + r;
      long long tv = is64 ? ((const long long*)tgt)[grow]
                          : (long long)((const int*)tgt)[grow];
#pragma unroll
      for (int nj = 0; nj < 4; nj++) {
        int gcol = col0 + wc * 64 + nj * 16 + fr;
        if (tv == (long long)gcol) picked[grow] = acc[mi][nj][r];
      }
    }
  }
}

// ---------------------------------------------------------------------------
// Per-row: S = sum of 250 partials; nll = log(S) - picked
// ---------------------------------------------------------------------------
__global__ void reduce_rows_kernel(const float* __restrict__ partialS,
                                   const float* __restrict__ picked,
                                   float* __restrict__ nll) {
  int r = blockIdx.x * blockDim.x + threadIdx.x;
  if (r >= BT) return;
  float S = 0.f;
  for (int cb = 0; cb < NCB; cb++) S += partialS[(size_t)cb * BT + r];
  nll[r] = logf(S) - picked[r];
}

// ---------------------------------------------------------------------------
// Final: loss = sum(nll) / n_non_ignore
// ---------------------------------------------------------------------------
__global__ void reduce_final_kernel(const float* __restrict__ nll,
                                    const void* __restrict__ tgt,
                                    const int* __restrict__ badcnt,
                                    float* __restrict__ out) {
  __shared__ float ssum[256];
  __shared__ int   scnt[256];
  int t = threadIdx.x;
  const bool is64 = (*badcnt == 0);
  float s = 0.f;
  int   c = 0;
  for (int r = t; r < BT; r += 256) {
    s += nll[r];
    long long tv = is64 ? ((const long long*)tgt)[r]
                        : (long long)((const int*)tgt)[r];
    c += (tv != (long long)IGNORE_IDX) ? 1 : 0;
  }
  ssum[t] = s;
  scnt[t] = c;
  __syncthreads();
  for (int o = 128; o > 0; o >>= 1) {
    if (t < o) {
      ssum[t] += ssum[t + o];
      scnt[t] += scnt[t + o];
    }
    __syncthreads();
  }
  if (t == 0) out[0] = ssum[0] / (float)scnt[0];
}

// ---------------------------------------------------------------------------
extern "C" void kernel_launch(void* const* d_in, const int* in_sizes, int n_in,
                              void* d_out, int out_size, void* d_ws,
                              size_t ws_size, hipStream_t stream) {
  const float* x   = (const float*)d_in[0];
  const float* w   = (const float*)d_in[1];
  const void*  tgt = d_in[2];
  float*       out = (float*)d_out;

  char* ws = (char*)d_ws;
  // ws layout:
  //   [0, offA)              : partialS (NCB*BT*4 = 4,096,000 B)
  //   [offA, offA+16)        : badcnt flag (+pad)
  //   [offA+16, +BT*4)       : picked
  //   [.. +BT*4)             : nll
  //   [offX, +BT*HD*2)       : x as bf16   (16,777,216 B)
  //   [offW, +VD*HD*2)       : W as bf16   (131,072,000 B)
  const size_t offA = (size_t)NCB * BT * 4;
  float* partialS   = (float*)ws;
  int*   badcnt     = (int*)(ws + offA);
  float* picked     = (float*)(ws + offA + 16);
  float* nll        = (float*)(ws + offA + 16 + (size_t)BT * 4);
  const size_t offX = offA + 16 + 2 * (size_t)BT * 4;   // 4,128,784 (16B-aligned)
  const size_t offW = offX + (size_t)BT * HD * 2;       // 20,906,000 (16B-aligned)
  const size_t need = offW + (size_t)VD * HD * 2;       // ~152 MB

  hipMemsetAsync(ws + offA, 0, 16 + (size_t)BT * 4, stream);

  detect_tgt_kernel<<<8, 256, 0, stream>>>((const long long*)tgt, badcnt);

  if (ws_size >= need) {
    unsigned short* xbf = (unsigned short*)(ws + offX);
    unsigned short* wbf = (unsigned short*)(ws + offW);
    cvt_bf16_kernel<<<2048, 256, 0, stream>>>(x, xbf, BT * HD / 8);
    cvt_bf16_kernel<<<2048, 256, 0, stream>>>(w, wbf, VD * HD / 8);
    gemm_lse_bf16_kernel<<<NRB * NCB, 256, 0, stream>>>(xbf, wbf, tgt, badcnt,
                                                        partialS, picked);
  } else {
    gemm_lse_kernel<<<NRB * NCB, 256, 0, stream>>>(x, w, tgt, badcnt, partialS,
                                                   picked);
  }

  reduce_rows_kernel<<<BT / 256, 256, 0, stream>>>(partialS, picked, nll);

  reduce_final_kernel<<<1, 256, 0, stream>>>(nll, tgt, badcnt, out);
}

// Round 5
// 878.354 us; speedup vs baseline: 1.7910x; 1.4971x over previous
//
#include <hip/hip_runtime.h>
#include <hip/hip_bf16.h>

// Problem constants (from reference)
#define BT 4096
#define HD 2048
#define VD 32000
#define IGNORE_IDX (-100)

// ---- 256x256 pipelined GEMM geometry (fast path) ----
#define BM2 256
#define BN2 256
#define BK2 32
#define NRB2 (BT / BM2)  // 16
#define NCB2 (VD / BN2)  // 125
#define NKT (HD / BK2)   // 64

// ---- 128x128 fallback geometry (fp32 path) ----
#define BM 128
#define BN 128
#define BKT 32
#define NRB (BT / BM)  // 32
#define NCB (VD / BN)  // 250

using short8 = __attribute__((ext_vector_type(8))) short;
using f32x4 = __attribute__((ext_vector_type(4))) float;

__device__ __forceinline__ unsigned short f2bf(float f) {
  unsigned u = __float_as_uint(f);
  u = (u + 0x7fffu + ((u >> 16) & 1u)) >> 16;
  return (unsigned short)u;
}

// async global->LDS, 16B/lane; LDS dest = wave-uniform base + lane*16.
// NOTE: offset param is ALWAYS 0 (R3/R4 NaN suspect: its side-of-application
// is ambiguous). All offsets are folded into the global pointer.
#define GL(SRC, DST)                                         \
  __builtin_amdgcn_global_load_lds(                          \
      (const __attribute__((address_space(1))) void*)(SRC),  \
      (__attribute__((address_space(3))) void*)(DST), 16, 0, 0)

// stage one half-tile (128 rows x 32 cols bf16 = 8KB): 1 GL per thread.
// KOFF in hw elements (bf16) relative to the wave's base global pointer.
#define STG1(GSRC, KOFF, DBASE, SLOT) GL((GSRC) + (KOFF), (DBASE) + (SLOT)*4096)

// ---------------------------------------------------------------------------
// Detect whether target buffer is int64 or int32 (reads 16KB, safe either way)
// ---------------------------------------------------------------------------
__global__ void detect_tgt_kernel(const long long* __restrict__ t64,
                                  int* __restrict__ badcnt) {
  int i = blockIdx.x * blockDim.x + threadIdx.x;  // 2048 threads
  long long v = t64[i];
  bool valid = (v == (long long)IGNORE_IDX) || (v >= 0 && v < (long long)VD);
  if (!valid) atomicAdd(badcnt, 1);
}

// ---------------------------------------------------------------------------
// fp32 -> bf16 bulk convert
// ---------------------------------------------------------------------------
__global__ void cvt_bf16_kernel(const float* __restrict__ in,
                                unsigned short* __restrict__ out, int n8) {
  int idx = blockIdx.x * blockDim.x + threadIdx.x;
  int stride = gridDim.x * blockDim.x;
  for (int i = idx; i < n8; i += stride) {
    float4 a = ((const float4*)in)[(size_t)2 * i];
    float4 b = ((const float4*)in)[(size_t)2 * i + 1];
    short8 o;
    o[0] = (short)f2bf(a.x);
    o[1] = (short)f2bf(a.y);
    o[2] = (short)f2bf(a.z);
    o[3] = (short)f2bf(a.w);
    o[4] = (short)f2bf(b.x);
    o[5] = (short)f2bf(b.y);
    o[6] = (short)f2bf(b.z);
    o[7] = (short)f2bf(b.w);
    ((short8*)out)[i] = o;
  }
}

// ---------------------------------------------------------------------------
// FAST PATH: 256x256 bf16 GEMM, BK=32, 64KB LDS double-buffer, counted-vmcnt
// pipeline (T1+T3+T4+T5), fused with per-(rowblock,colblock) sum(exp(logit))
// and picked-target-logit.
//
// LDS slots (4096 hw each): slot = buf*2 + half. Linear [128][32] layout:
// offset(row,col) = row*32 + col (hw). All staged via offset-0 gload_lds.
// 8 waves (2M x 4N); per-wave output 128x64; acc[8][4] f32x4.
// Per K-tile: 12 ds_read_b128 at top, then 2 phases (M-half x 16 MFMA).
// Stage A(kt+2) after Ph1, B(kt+2) after Ph2; vmcnt(2) before each Ph2
// (guards tile kt+1); vmcnt(0) only at tail boundary.
// LDS is zero-initialized so ANY residual schedule bug yields finite-wrong
// output (diagnosable), never NaN.
// ---------------------------------------------------------------------------
__global__ __launch_bounds__(512) void gemm_lse_pipe_kernel(
    const unsigned short* __restrict__ xbf,
    const unsigned short* __restrict__ wbf, const void* __restrict__ tgt,
    const int* __restrict__ badcnt, float* __restrict__ partialS,
    float* __restrict__ picked) {
  __shared__ unsigned short smem[32768];  // 64 KB
  unsigned short* ldsA = smem;            // 4 * 4096 hw
  unsigned short* ldsB = smem + 16384;

  const int t = threadIdx.x;

  // zero-init LDS (8 x 16B stores per thread), full fence after
  {
    uint4 z = make_uint4(0u, 0u, 0u, 0u);
#pragma unroll
    for (int i = 0; i < 8; i++) ((uint4*)smem)[t + i * 512] = z;
  }
  __syncthreads();

  // T1: bijective XCD swizzle (2000 % 8 == 0), rowblock-fast
  const int bid = blockIdx.x;
  const int cpx = (NRB2 * NCB2) >> 3;  // 250
  const int swz = (bid & 7) * cpx + (bid >> 3);
  const int rb = swz % NRB2;
  const int cb = swz / NRB2;
  const int row0 = rb * BM2;
  const int col0 = cb * BN2;

  const int lane = t & 63;
  const int w = t >> 6;    // 0..7
  const int wm = w >> 2;   // 0..1  (A half)
  const int wn = w & 3;    // 0..3
  const int bh = wn >> 1;  // B half
  const int bn4 = wn & 1;  // 64-row subrange within B half

  const int fr = lane & 15;
  const int kq = lane >> 4;  // 0..3

  // read-side LDS offsets (linear, no swizzle)
  const int aoff = fr * 32 + kq * 8;
  const unsigned short* pA0 = ldsA + (0 * 2 + wm) * 4096 + aoff;
  const unsigned short* pA1 = ldsA + (1 * 2 + wm) * 4096 + aoff;
  const unsigned short* pB0 = ldsB + (0 * 2 + bh) * 4096 + bn4 * 2048 + aoff;
  const unsigned short* pB1 = ldsB + (1 * 2 + bh) * 4096 + bn4 * 2048 + aoff;

  // staging geometry: wave w stages rows w*16..w*16+15 of each half-tile;
  // lane l covers (srow = l>>2, cols (l&3)*8 .. +7) -> LDS linear l*16B.
  const int srow = lane >> 2;
  const int scol = (lane & 3) * 8;
  const unsigned short* gA0 =
      xbf + (size_t)(row0 + 0 + w * 16 + srow) * HD + scol;
  const unsigned short* gA1 =
      xbf + (size_t)(row0 + 128 + w * 16 + srow) * HD + scol;
  const unsigned short* gB0 =
      wbf + (size_t)(col0 + 0 + w * 16 + srow) * HD + scol;
  const unsigned short* gB1 =
      wbf + (size_t)(col0 + 128 + w * 16 + srow) * HD + scol;

  unsigned short* dA = ldsA + w * 512;  // wave's 1KB region within a slot
  unsigned short* dB = ldsB + w * 512;

  f32x4 acc[8][4];
#pragma unroll
  for (int i = 0; i < 8; i++)
#pragma unroll
    for (int n = 0; n < 4; n++)
#pragma unroll
      for (int q = 0; q < 4; q++) acc[i][n][q] = 0.f;

  short8 aR[8], bR[4];

#define RD12(PA, PB)                                   \
  _Pragma("unroll") for (int i = 0; i < 8; i++)        \
      aR[i] = *(const short8*)((PA) + i * 512);        \
  _Pragma("unroll") for (int n = 0; n < 4; n++)        \
      bR[n] = *(const short8*)((PB) + n * 512);

#define MMQ(MH)                                                       \
  _Pragma("unroll") for (int i = 0; i < 4; i++)                       \
  _Pragma("unroll") for (int n = 0; n < 4; n++)                       \
      acc[(MH)*4 + i][n] = __builtin_amdgcn_mfma_f32_16x16x32_bf16(   \
          aR[(MH)*4 + i], bR[n], acc[(MH)*4 + i][n], 0, 0, 0);

#define PHASE(MH)                                      \
  __builtin_amdgcn_sched_barrier(0);                   \
  __builtin_amdgcn_s_barrier();                        \
  asm volatile("s_waitcnt lgkmcnt(0)" ::: "memory");   \
  __builtin_amdgcn_sched_barrier(0);                   \
  __builtin_amdgcn_s_setprio(1);                       \
  MMQ(MH);                                             \
  __builtin_amdgcn_s_setprio(0);                       \
  __builtin_amdgcn_sched_barrier(0);                   \
  __builtin_amdgcn_s_barrier();                        \
  __builtin_amdgcn_sched_barrier(0);

  // ---- prologue: stage K-tiles 0 (buf0) and 1 (buf1); wait tile0 ----
  STG1(gA0, 0, dA, 0);   // A0(0)
  STG1(gA1, 0, dA, 1);   // A1(0)
  STG1(gB0, 0, dB, 0);   // B0(0)
  STG1(gB1, 0, dB, 1);   // B1(0)
  STG1(gA0, 32, dA, 2);  // A0(1)
  STG1(gA1, 32, dA, 3);  // A1(1)
  STG1(gB0, 32, dB, 2);  // B0(1)
  STG1(gB1, 32, dB, 3);  // B1(1)
  asm volatile("s_waitcnt vmcnt(4)" ::: "memory");  // tile0 landed
  __builtin_amdgcn_s_barrier();

  // ---- main loop: 2 K-tiles / iter; stages tiles kt+2, kt+3 ----
  // vmcnt ledger (steady state): at loop top 4 outstanding (tile kt+1);
  // +2 after A-stage -> vmcnt(2) drains tile kt+1; +2 B, +2 A -> vmcnt(2)
  // drains tile kt+2; +2 B -> 4 at loop bottom. No other vmem ops exist
  // between the memory-clobber asms (compiler cannot cross them).
  for (int kt = 0; kt + 3 < NKT; kt += 2) {
    // K-tile kt (buf0)
    RD12(pA0, pB0);
    PHASE(0);
    STG1(gA0, 64, dA, 0);  // A0(kt+2): slot0 reads done at phase close
    STG1(gA1, 64, dA, 1);  // A1(kt+2)
    asm volatile("s_waitcnt vmcnt(2)" ::: "memory");  // tile kt+1 landed
    PHASE(1);
    STG1(gB0, 64, dB, 0);  // B0(kt+2)
    STG1(gB1, 64, dB, 1);  // B1(kt+2)
    // K-tile kt+1 (buf1)
    RD12(pA1, pB1);
    PHASE(0);
    STG1(gA0, 96, dA, 2);  // A0(kt+3)
    STG1(gA1, 96, dA, 3);  // A1(kt+3)
    asm volatile("s_waitcnt vmcnt(2)" ::: "memory");  // tile kt+2 landed
    PHASE(1);
    STG1(gB0, 96, dB, 2);  // B0(kt+3)
    STG1(gB1, 96, dB, 3);  // B1(kt+3)
    gA0 += 64;  // advance 2 K-tiles (64 hw = 128 B)
    gA1 += 64;
    gB0 += 64;
    gB1 += 64;
  }

  // ---- tail: K-tiles NKT-2 (buf0), NKT-1 (buf1); no more staging ----
  {
    RD12(pA0, pB0);
    PHASE(0);
    asm volatile("s_waitcnt vmcnt(0)" ::: "memory");  // tile NKT-1 landed
    PHASE(1);
    RD12(pA1, pB1);
    PHASE(0);
    PHASE(1);
  }

  // ---- epilogue: per-row sum(exp) over this block's 256 cols ----
  // C/D layout: col = col0 + wn*64 + n*16 + fr ;
  //             row = row0 + wm*128 + i*16 + kq*4 + q
  __syncthreads();
  float* red = (float*)smem;  // [256 rows][4 wn] floats = 4KB
#pragma unroll
  for (int i = 0; i < 8; i++) {
#pragma unroll
    for (int q = 0; q < 4; q++) {
      float s = 0.f;
#pragma unroll
      for (int n = 0; n < 4; n++) s += expf(acc[i][n][q]);
#pragma unroll
      for (int m = 1; m < 16; m <<= 1) s += __shfl_xor(s, m, 64);
      if (fr == 0) red[(wm * 128 + i * 16 + kq * 4 + q) * 4 + wn] = s;
    }
  }
  __syncthreads();
  if (t < 256) {
    float S = red[t * 4 + 0] + red[t * 4 + 1] + red[t * 4 + 2] + red[t * 4 + 3];
    partialS[(size_t)cb * BT + row0 + t] = S;
  }

  // ---- picked target logit (single writer per row across the grid) ----
  const bool is64 = (*badcnt == 0);
#pragma unroll
  for (int i = 0; i < 8; i++) {
#pragma unroll
    for (int q = 0; q < 4; q++) {
      int grow = row0 + wm * 128 + i * 16 + kq * 4 + q;
      long long tv = is64 ? ((const long long*)tgt)[grow]
                          : (long long)((const int*)tgt)[grow];
#pragma unroll
      for (int n = 0; n < 4; n++) {
        int gcol = col0 + wn * 64 + n * 16 + fr;
        if (tv == (long long)gcol) picked[grow] = acc[i][n][q];
      }
    }
  }
#undef RD12
#undef MMQ
#undef PHASE
}

// ---------------------------------------------------------------------------
// FALLBACK PATH (ws too small): fp32 inputs with on-the-fly cvt
// ---------------------------------------------------------------------------
__global__ __launch_bounds__(256) void gemm_lse_kernel(
    const float* __restrict__ x, const float* __restrict__ w,
    const void* __restrict__ tgt, const int* __restrict__ badcnt,
    float* __restrict__ partialS, float* __restrict__ picked) {
  __shared__ unsigned short As[BM][BKT];
  __shared__ unsigned short Bs[BN][BKT];

  const int bid = blockIdx.x;
  const int rb = bid % NRB;
  const int cb = bid / NRB;
  const int row0 = rb * BM;
  const int col0 = cb * BN;
  const int t = threadIdx.x;
  const int lane = t & 63;
  const int wave = t >> 6;
  const int wr = wave >> 1;
  const int wc = wave & 1;

  const int srow = t >> 3;
  const int scol = (t & 7) * 4;

  const float* xA = x + (size_t)row0 * HD;
  const float* wB = w + (size_t)col0 * HD;

  f32x4 acc[4][4];
#pragma unroll
  for (int i = 0; i < 4; i++)
#pragma unroll
    for (int j = 0; j < 4; j++)
#pragma unroll
      for (int q = 0; q < 4; q++) acc[i][j][q] = 0.f;

  float4 ra[4], rbv[4];

#define STAGE_LOAD(k0)                                                        \
  {                                                                           \
    _Pragma("unroll") for (int j = 0; j < 4; j++) {                           \
      ra[j] = *(const float4*)(xA + (size_t)(srow + j * 32) * HD + (k0) + scol); \
      rbv[j] = *(const float4*)(wB + (size_t)(srow + j * 32) * HD + (k0) + scol); \
    }                                                                         \
  }
#define STAGE_WRITE()                                                         \
  {                                                                           \
    _Pragma("unroll") for (int j = 0; j < 4; j++) {                           \
      ushort4 pa = make_ushort4(f2bf(ra[j].x), f2bf(ra[j].y), f2bf(ra[j].z),  \
                                f2bf(ra[j].w));                               \
      ushort4 pb = make_ushort4(f2bf(rbv[j].x), f2bf(rbv[j].y),               \
                                f2bf(rbv[j].z), f2bf(rbv[j].w));              \
      *(ushort4*)&As[srow + j * 32][scol] = pa;                               \
      *(ushort4*)&Bs[srow + j * 32][scol] = pb;                               \
    }                                                                         \
  }

  const int ks = (lane >> 4) * 8;
  const int fr = lane & 15;

  STAGE_LOAD(0);
  STAGE_WRITE();
  __syncthreads();

  for (int k0 = 0; k0 < HD; k0 += BKT) {
    const bool notlast = (k0 + BKT < HD);
    if (notlast) STAGE_LOAD(k0 + BKT);

    short8 af[4], bfv[4];
#pragma unroll
    for (int i = 0; i < 4; i++) {
      af[i] = *(const short8*)&As[wr * 64 + i * 16 + fr][ks];
      bfv[i] = *(const short8*)&Bs[wc * 64 + i * 16 + fr][ks];
    }
#pragma unroll
    for (int i = 0; i < 4; i++)
#pragma unroll
      for (int j = 0; j < 4; j++)
        acc[i][j] = __builtin_amdgcn_mfma_f32_16x16x32_bf16(af[i], bfv[j],
                                                            acc[i][j], 0, 0, 0);

    __syncthreads();
    if (notlast) STAGE_WRITE();
    __syncthreads();
  }
#undef STAGE_LOAD
#undef STAGE_WRITE

  float rsum[16];
#pragma unroll
  for (int mi = 0; mi < 4; mi++) {
#pragma unroll
    for (int r = 0; r < 4; r++) {
      float s = 0.f;
#pragma unroll
      for (int nj = 0; nj < 4; nj++) s += expf(acc[mi][nj][r]);
      rsum[mi * 4 + r] = s;
    }
  }
#pragma unroll
  for (int m = 1; m < 16; m <<= 1) {
#pragma unroll
    for (int q = 0; q < 16; q++) rsum[q] += __shfl_xor(rsum[q], m, 64);
  }

  __syncthreads();
  float* red = (float*)&As[0][0];
  if (fr == 0) {
#pragma unroll
    for (int mi = 0; mi < 4; mi++)
#pragma unroll
      for (int r = 0; r < 4; r++)
        red[wave * 64 + mi * 16 + (lane >> 4) * 4 + r] = rsum[mi * 4 + r];
  }
  __syncthreads();

  if (t < BM) {
    int rl = t;
    int wrow = rl >> 6;
    float S = red[(wrow * 2 + 0) * 64 + (rl & 63)] +
              red[(wrow * 2 + 1) * 64 + (rl & 63)];
    partialS[(size_t)cb * BT + row0 + rl] = S;
  }

  const bool is64 = (*badcnt == 0);
#pragma unroll
  for (int mi = 0; mi < 4; mi++) {
#pragma unroll
    for (int r = 0; r < 4; r++) {
      int grow = row0 + wr * 64 + mi * 16 + ((lane >> 4) << 2) + r;
      long long tv = is64 ? ((const long long*)tgt)[grow]
                          : (long long)((const int*)tgt)[grow];
#pragma unroll
      for (int nj = 0; nj < 4; nj++) {
        int gcol = col0 + wc * 64 + nj * 16 + fr;
        if (tv == (long long)gcol) picked[grow] = acc[mi][nj][r];
      }
    }
  }
}

// ---------------------------------------------------------------------------
// Per-row: S = sum of ncb partials; nll = log(S) - picked.
// Clamp keeps the loss finite even if partialS was never written (poison) --
// turns any upstream failure into a finite, diagnosable absmax.
// ---------------------------------------------------------------------------
__global__ void reduce_rows_kernel(const float* __restrict__ partialS,
                                   const float* __restrict__ picked,
                                   float* __restrict__ nll, int ncb) {
  int r = blockIdx.x * blockDim.x + threadIdx.x;
  if (r >= BT) return;
  float S = 0.f;
  for (int cb = 0; cb < ncb; cb++) S += partialS[(size_t)cb * BT + r];
  nll[r] = logf(fmaxf(S, 1e-37f)) - picked[r];
}

// ---------------------------------------------------------------------------
// Final: loss = sum(nll) / n_non_ignore
// ---------------------------------------------------------------------------
__global__ void reduce_final_kernel(const float* __restrict__ nll,
                                    const void* __restrict__ tgt,
                                    const int* __restrict__ badcnt,
                                    float* __restrict__ out) {
  __shared__ float ssum[256];
  __shared__ int scnt[256];
  int t = threadIdx.x;
  const bool is64 = (*badcnt == 0);
  float s = 0.f;
  int c = 0;
  for (int r = t; r < BT; r += 256) {
    s += nll[r];
    long long tv =
        is64 ? ((const long long*)tgt)[r] : (long long)((const int*)tgt)[r];
    c += (tv != (long long)IGNORE_IDX) ? 1 : 0;
  }
  ssum[t] = s;
  scnt[t] = c;
  __syncthreads();
  for (int o = 128; o > 0; o >>= 1) {
    if (t < o) {
      ssum[t] += ssum[t + o];
      scnt[t] += scnt[t + o];
    }
    __syncthreads();
  }
  if (t == 0) out[0] = ssum[0] / (float)scnt[0];
}

// ---------------------------------------------------------------------------
extern "C" void kernel_launch(void* const* d_in, const int* in_sizes, int n_in,
                              void* d_out, int out_size, void* d_ws,
                              size_t ws_size, hipStream_t stream) {
  const float* x = (const float*)d_in[0];
  const float* w = (const float*)d_in[1];
  const void* tgt = d_in[2];
  float* out = (float*)d_out;

  char* ws = (char*)d_ws;
  // ws layout:
  //   [0, offA)              : partialS (NCB*BT*4 = 4,096,000 B max)
  //   [offA, offA+16)        : badcnt flag (+pad)
  //   [offA+16, +BT*4)       : picked
  //   [.. +BT*4)             : nll
  //   [offX, +BT*HD*2)       : x as bf16
  //   [offW, +VD*HD*2)       : W as bf16
  const size_t offA = (size_t)NCB * BT * 4;
  float* partialS = (float*)ws;
  int* badcnt = (int*)(ws + offA);
  float* picked = (float*)(ws + offA + 16);
  float* nll = (float*)(ws + offA + 16 + (size_t)BT * 4);
  const size_t offX = offA + 16 + 2 * (size_t)BT * 4;
  const size_t offW = offX + (size_t)BT * HD * 2;
  const size_t need = offW + (size_t)VD * HD * 2;

  hipMemsetAsync(ws + offA, 0, 16 + (size_t)BT * 4, stream);

  detect_tgt_kernel<<<8, 256, 0, stream>>>((const long long*)tgt, badcnt);

  if (ws_size >= need) {
    unsigned short* xbf = (unsigned short*)(ws + offX);
    unsigned short* wbf = (unsigned short*)(ws + offW);
    cvt_bf16_kernel<<<2048, 256, 0, stream>>>(x, xbf, BT * HD / 8);
    cvt_bf16_kernel<<<2048, 256, 0, stream>>>(w, wbf, VD * HD / 8);
    gemm_lse_pipe_kernel<<<NRB2 * NCB2, 512, 0, stream>>>(xbf, wbf, tgt,
                                                          badcnt, partialS,
                                                          picked);
    reduce_rows_kernel<<<BT / 256, 256, 0, stream>>>(partialS, picked, nll,
                                                     NCB2);
  } else {
    gemm_lse_kernel<<<NRB * NCB, 256, 0, stream>>>(x, w, tgt, badcnt, partialS,
                                                   picked);
    reduce_rows_kernel<<<BT / 256, 256, 0, stream>>>(partialS, picked, nll,
                                                     NCB);
  }

  reduce_final_kernel<<<1, 256, 0, stream>>>(nll, tgt, badcnt, out);
}

// Round 6
// 854.858 us; speedup vs baseline: 1.8402x; 1.0275x over previous
//
#include <hip/hip_runtime.h>
#include <hip/hip_bf16.h>

// Problem constants (from reference)
#define BT 4096
#define HD 2048
#define VD 32000
#define IGNORE_IDX (-100)

// ---- 256x256 pipelined GEMM geometry (fast path) ----
#define BM2 256
#define BN2 256
#define BK2 32
#define NRB2 (BT / BM2)  // 16
#define NCB2 (VD / BN2)  // 125
#define NKT (HD / BK2)   // 64

// ---- 128x128 fallback geometry (fp32 path) ----
#define BM 128
#define BN 128
#define BKT 32
#define NRB (BT / BM)  // 32
#define NCB (VD / BN)  // 250

using short8 = __attribute__((ext_vector_type(8))) short;
using f32x4 = __attribute__((ext_vector_type(4))) float;

__device__ __forceinline__ unsigned short f2bf(float f) {
  unsigned u = __float_as_uint(f);
  u = (u + 0x7fffu + ((u >> 16) & 1u)) >> 16;
  return (unsigned short)u;
}

// async global->LDS, 16B/lane; LDS dest = wave-uniform base + lane*16.
// NOTE: offset param MUST stay 0 (R3/R4 NaN root cause). All offsets are
// folded into the global pointer.
#define GL(SRC, DST)                                         \
  __builtin_amdgcn_global_load_lds(                          \
      (const __attribute__((address_space(1))) void*)(SRC),  \
      (__attribute__((address_space(3))) void*)(DST), 16, 0, 0)

// stage one half-tile (128 rows x 32 cols bf16 = 8KB): 1 GL per thread.
// KOFF in hw elements (bf16) relative to the wave's base global pointer.
#define STG1(GSRC, KOFF, DBASE, SLOT) GL((GSRC) + (KOFF), (DBASE) + (SLOT)*4096)

// ---------------------------------------------------------------------------
// Detect whether target buffer is int64 or int32 (reads 16KB, safe either way)
// ---------------------------------------------------------------------------
__global__ void detect_tgt_kernel(const long long* __restrict__ t64,
                                  int* __restrict__ badcnt) {
  int i = blockIdx.x * blockDim.x + threadIdx.x;  // 2048 threads
  long long v = t64[i];
  bool valid = (v == (long long)IGNORE_IDX) || (v >= 0 && v < (long long)VD);
  if (!valid) atomicAdd(badcnt, 1);
}

// ---------------------------------------------------------------------------
// fp32 -> bf16 bulk convert
// ---------------------------------------------------------------------------
__global__ void cvt_bf16_kernel(const float* __restrict__ in,
                                unsigned short* __restrict__ out, int n8) {
  int idx = blockIdx.x * blockDim.x + threadIdx.x;
  int stride = gridDim.x * blockDim.x;
  for (int i = idx; i < n8; i += stride) {
    float4 a = ((const float4*)in)[(size_t)2 * i];
    float4 b = ((const float4*)in)[(size_t)2 * i + 1];
    short8 o;
    o[0] = (short)f2bf(a.x);
    o[1] = (short)f2bf(a.y);
    o[2] = (short)f2bf(a.z);
    o[3] = (short)f2bf(a.w);
    o[4] = (short)f2bf(b.x);
    o[5] = (short)f2bf(b.y);
    o[6] = (short)f2bf(b.z);
    o[7] = (short)f2bf(b.w);
    ((short8*)out)[i] = o;
  }
}

// ---------------------------------------------------------------------------
// FAST PATH: 256x256 bf16 GEMM, BK=32, 64KB LDS double-buffer, counted-vmcnt
// pipeline (T1+T3+T4+T5), fused with per-(rowblock,colblock) sum(exp(logit))
// and picked-target-logit.
//
// LDS slots (4096 hw each): slot = buf*2 + half. FRAGMENT-ORDER layout:
// a half-tile (128 rows x 32 k) is stored as [i16blk 0..7][kq 0..3][fr 0..15]
// x 8 hw, i.e. element (row = 16*i + fr, k = kq*8..+7) lives at hw offset
// (i*64 + kq*16 + fr)*8. Staging stays LDS-linear (lane l writes l*16B);
// the per-lane GLOBAL source is permuted instead (srow = lane&15,
// scol = (lane>>4)*8). Frag ds_read_b128 is then lane-linear: lane l reads
// byte l*16 of a contiguous 1KB block -> ZERO bank conflicts (was 8-way).
// 8 waves (2M x 4N); per-wave output 128x64; acc[8][4] f32x4.
// Per K-tile: 12 ds_read_b128 at top, then 2 phases (M-half x 16 MFMA).
// Stage A(kt+2) after Ph1, B(kt+2) after Ph2; vmcnt(2) before each Ph2;
// vmcnt(0) only at tail boundary.
// ---------------------------------------------------------------------------
__global__ __launch_bounds__(512) void gemm_lse_pipe_kernel(
    const unsigned short* __restrict__ xbf,
    const unsigned short* __restrict__ wbf, const void* __restrict__ tgt,
    const int* __restrict__ badcnt, float* __restrict__ partialS,
    float* __restrict__ picked) {
  __shared__ unsigned short smem[32768];  // 64 KB
  unsigned short* ldsA = smem;            // 4 * 4096 hw
  unsigned short* ldsB = smem + 16384;

  const int t = threadIdx.x;

  // zero-init LDS (8 x 16B stores per thread), full fence after
  {
    uint4 z = make_uint4(0u, 0u, 0u, 0u);
#pragma unroll
    for (int i = 0; i < 8; i++) ((uint4*)smem)[t + i * 512] = z;
  }
  __syncthreads();

  // T1: bijective XCD swizzle (2000 % 8 == 0), rowblock-fast
  const int bid = blockIdx.x;
  const int cpx = (NRB2 * NCB2) >> 3;  // 250
  const int swz = (bid & 7) * cpx + (bid >> 3);
  const int rb = swz % NRB2;
  const int cb = swz / NRB2;
  const int row0 = rb * BM2;
  const int col0 = cb * BN2;

  const int lane = t & 63;
  const int w = t >> 6;    // 0..7
  const int wm = w >> 2;   // 0..1  (A half)
  const int wn = w & 3;    // 0..3
  const int bh = wn >> 1;  // B half
  const int bn4 = wn & 1;  // 64-row subrange within B half

  const int fr = lane & 15;
  const int kq = lane >> 4;  // 0..3

  // read-side LDS offsets (fragment-order): lane-linear, conflict-free
  const int aoff = lane * 8;  // = (kq*16 + fr) * 8 hw
  const unsigned short* pA0 = ldsA + (0 * 2 + wm) * 4096 + aoff;
  const unsigned short* pA1 = ldsA + (1 * 2 + wm) * 4096 + aoff;
  const unsigned short* pB0 = ldsB + (0 * 2 + bh) * 4096 + bn4 * 2048 + aoff;
  const unsigned short* pB1 = ldsB + (1 * 2 + bh) * 4096 + bn4 * 2048 + aoff;

  // staging geometry: wave w stages 16-row block i=w of each half-tile;
  // lane l = kq*16 + fr sources global (row = w*16 + (l&15), k = (l>>4)*8)
  // and lands at LDS linear l*16B -> fragment-order layout.
  const int srow = lane & 15;
  const int scol = (lane >> 4) * 8;
  const unsigned short* gA0 =
      xbf + (size_t)(row0 + 0 + w * 16 + srow) * HD + scol;
  const unsigned short* gA1 =
      xbf + (size_t)(row0 + 128 + w * 16 + srow) * HD + scol;
  const unsigned short* gB0 =
      wbf + (size_t)(col0 + 0 + w * 16 + srow) * HD + scol;
  const unsigned short* gB1 =
      wbf + (size_t)(col0 + 128 + w * 16 + srow) * HD + scol;

  unsigned short* dA = ldsA + w * 512;  // wave's 1KB region within a slot
  unsigned short* dB = ldsB + w * 512;

  f32x4 acc[8][4];
#pragma unroll
  for (int i = 0; i < 8; i++)
#pragma unroll
    for (int n = 0; n < 4; n++)
#pragma unroll
      for (int q = 0; q < 4; q++) acc[i][n][q] = 0.f;

  short8 aR[8], bR[4];

#define RD12(PA, PB)                                   \
  _Pragma("unroll") for (int i = 0; i < 8; i++)        \
      aR[i] = *(const short8*)((PA) + i * 512);        \
  _Pragma("unroll") for (int n = 0; n < 4; n++)        \
      bR[n] = *(const short8*)((PB) + n * 512);

#define MMQ(MH)                                                       \
  _Pragma("unroll") for (int i = 0; i < 4; i++)                       \
  _Pragma("unroll") for (int n = 0; n < 4; n++)                       \
      acc[(MH)*4 + i][n] = __builtin_amdgcn_mfma_f32_16x16x32_bf16(   \
          aR[(MH)*4 + i], bR[n], acc[(MH)*4 + i][n], 0, 0, 0);

#define PHASE(MH)                                      \
  __builtin_amdgcn_sched_barrier(0);                   \
  __builtin_amdgcn_s_barrier();                        \
  asm volatile("s_waitcnt lgkmcnt(0)" ::: "memory");   \
  __builtin_amdgcn_sched_barrier(0);                   \
  __builtin_amdgcn_s_setprio(1);                       \
  MMQ(MH);                                             \
  __builtin_amdgcn_s_setprio(0);                       \
  __builtin_amdgcn_sched_barrier(0);                   \
  __builtin_amdgcn_s_barrier();                        \
  __builtin_amdgcn_sched_barrier(0);

  // ---- prologue: stage K-tiles 0 (buf0) and 1 (buf1); wait tile0 ----
  STG1(gA0, 0, dA, 0);   // A0(0)
  STG1(gA1, 0, dA, 1);   // A1(0)
  STG1(gB0, 0, dB, 0);   // B0(0)
  STG1(gB1, 0, dB, 1);   // B1(0)
  STG1(gA0, 32, dA, 2);  // A0(1)
  STG1(gA1, 32, dA, 3);  // A1(1)
  STG1(gB0, 32, dB, 2);  // B0(1)
  STG1(gB1, 32, dB, 3);  // B1(1)
  asm volatile("s_waitcnt vmcnt(4)" ::: "memory");  // tile0 landed
  __builtin_amdgcn_s_barrier();

  // ---- main loop: 2 K-tiles / iter; stages tiles kt+2, kt+3 ----
  // vmcnt ledger (steady state): at loop top 4 outstanding (tile kt+1);
  // +2 after A-stage -> vmcnt(2) drains tile kt+1; +2 B, +2 A -> vmcnt(2)
  // drains tile kt+2; +2 B -> 4 at loop bottom.
  for (int kt = 0; kt + 3 < NKT; kt += 2) {
    // K-tile kt (buf0)
    RD12(pA0, pB0);
    PHASE(0);
    STG1(gA0, 64, dA, 0);  // A0(kt+2): slot0 reads done at phase close
    STG1(gA1, 64, dA, 1);  // A1(kt+2)
    asm volatile("s_waitcnt vmcnt(2)" ::: "memory");  // tile kt+1 landed
    PHASE(1);
    STG1(gB0, 64, dB, 0);  // B0(kt+2)
    STG1(gB1, 64, dB, 1);  // B1(kt+2)
    // K-tile kt+1 (buf1)
    RD12(pA1, pB1);
    PHASE(0);
    STG1(gA0, 96, dA, 2);  // A0(kt+3)
    STG1(gA1, 96, dA, 3);  // A1(kt+3)
    asm volatile("s_waitcnt vmcnt(2)" ::: "memory");  // tile kt+2 landed
    PHASE(1);
    STG1(gB0, 96, dB, 2);  // B0(kt+3)
    STG1(gB1, 96, dB, 3);  // B1(kt+3)
    gA0 += 64;  // advance 2 K-tiles (64 hw = 128 B)
    gA1 += 64;
    gB0 += 64;
    gB1 += 64;
  }

  // ---- tail: K-tiles NKT-2 (buf0), NKT-1 (buf1); no more staging ----
  {
    RD12(pA0, pB0);
    PHASE(0);
    asm volatile("s_waitcnt vmcnt(0)" ::: "memory");  // tile NKT-1 landed
    PHASE(1);
    RD12(pA1, pB1);
    PHASE(0);
    PHASE(1);
  }

  // ---- epilogue: per-row sum(exp) over this block's 256 cols ----
  // C/D layout: col = col0 + wn*64 + n*16 + fr ;
  //             row = row0 + wm*128 + i*16 + kq*4 + q
  __syncthreads();
  float* red = (float*)smem;  // [256 rows][4 wn] floats = 4KB
#pragma unroll
  for (int i = 0; i < 8; i++) {
#pragma unroll
    for (int q = 0; q < 4; q++) {
      float s = 0.f;
#pragma unroll
      for (int n = 0; n < 4; n++) s += expf(acc[i][n][q]);
#pragma unroll
      for (int m = 1; m < 16; m <<= 1) s += __shfl_xor(s, m, 64);
      if (fr == 0) red[(wm * 128 + i * 16 + kq * 4 + q) * 4 + wn] = s;
    }
  }
  __syncthreads();
  if (t < 256) {
    float S = red[t * 4 + 0] + red[t * 4 + 1] + red[t * 4 + 2] + red[t * 4 + 3];
    partialS[(size_t)cb * BT + row0 + t] = S;
  }

  // ---- picked target logit (single writer per row across the grid) ----
  const bool is64 = (*badcnt == 0);
#pragma unroll
  for (int i = 0; i < 8; i++) {
#pragma unroll
    for (int q = 0; q < 4; q++) {
      int grow = row0 + wm * 128 + i * 16 + kq * 4 + q;
      long long tv = is64 ? ((const long long*)tgt)[grow]
                          : (long long)((const int*)tgt)[grow];
#pragma unroll
      for (int n = 0; n < 4; n++) {
        int gcol = col0 + wn * 64 + n * 16 + fr;
        if (tv == (long long)gcol) picked[grow] = acc[i][n][q];
      }
    }
  }
#undef RD12
#undef MMQ
#undef PHASE
}

// ---------------------------------------------------------------------------
// FALLBACK PATH (ws too small): fp32 inputs with on-the-fly cvt
// ---------------------------------------------------------------------------
__global__ __launch_bounds__(256) void gemm_lse_kernel(
    const float* __restrict__ x, const float* __restrict__ w,
    const void* __restrict__ tgt, const int* __restrict__ badcnt,
    float* __restrict__ partialS, float* __restrict__ picked) {
  __shared__ unsigned short As[BM][BKT];
  __shared__ unsigned short Bs[BN][BKT];

  const int bid = blockIdx.x;
  const int rb = bid % NRB;
  const int cb = bid / NRB;
  const int row0 = rb * BM;
  const int col0 = cb * BN;
  const int t = threadIdx.x;
  const int lane = t & 63;
  const int wave = t >> 6;
  const int wr = wave >> 1;
  const int wc = wave & 1;

  const int srow = t >> 3;
  const int scol = (t & 7) * 4;

  const float* xA = x + (size_t)row0 * HD;
  const float* wB = w + (size_t)col0 * HD;

  f32x4 acc[4][4];
#pragma unroll
  for (int i = 0; i < 4; i++)
#pragma unroll
    for (int j = 0; j < 4; j++)
#pragma unroll
      for (int q = 0; q < 4; q++) acc[i][j][q] = 0.f;

  float4 ra[4], rbv[4];

#define STAGE_LOAD(k0)                                                        \
  {                                                                           \
    _Pragma("unroll") for (int j = 0; j < 4; j++) {                           \
      ra[j] = *(const float4*)(xA + (size_t)(srow + j * 32) * HD + (k0) + scol); \
      rbv[j] = *(const float4*)(wB + (size_t)(srow + j * 32) * HD + (k0) + scol); \
    }                                                                         \
  }
#define STAGE_WRITE()                                                         \
  {                                                                           \
    _Pragma("unroll") for (int j = 0; j < 4; j++) {                           \
      ushort4 pa = make_ushort4(f2bf(ra[j].x), f2bf(ra[j].y), f2bf(ra[j].z),  \
                                f2bf(ra[j].w));                               \
      ushort4 pb = make_ushort4(f2bf(rbv[j].x), f2bf(rbv[j].y),               \
                                f2bf(rbv[j].z), f2bf(rbv[j].w));              \
      *(ushort4*)&As[srow + j * 32][scol] = pa;                               \
      *(ushort4*)&Bs[srow + j * 32][scol] = pb;                               \
    }                                                                         \
  }

  const int ks = (lane >> 4) * 8;
  const int fr = lane & 15;

  STAGE_LOAD(0);
  STAGE_WRITE();
  __syncthreads();

  for (int k0 = 0; k0 < HD; k0 += BKT) {
    const bool notlast = (k0 + BKT < HD);
    if (notlast) STAGE_LOAD(k0 + BKT);

    short8 af[4], bfv[4];
#pragma unroll
    for (int i = 0; i < 4; i++) {
      af[i] = *(const short8*)&As[wr * 64 + i * 16 + fr][ks];
      bfv[i] = *(const short8*)&Bs[wc * 64 + i * 16 + fr][ks];
    }
#pragma unroll
    for (int i = 0; i < 4; i++)
#pragma unroll
      for (int j = 0; j < 4; j++)
        acc[i][j] = __builtin_amdgcn_mfma_f32_16x16x32_bf16(af[i], bfv[j],
                                                            acc[i][j], 0, 0, 0);

    __syncthreads();
    if (notlast) STAGE_WRITE();
    __syncthreads();
  }
#undef STAGE_LOAD
#undef STAGE_WRITE

  float rsum[16];
#pragma unroll
  for (int mi = 0; mi < 4; mi++) {
#pragma unroll
    for (int r = 0; r < 4; r++) {
      float s = 0.f;
#pragma unroll
      for (int nj = 0; nj < 4; nj++) s += expf(acc[mi][nj][r]);
      rsum[mi * 4 + r] = s;
    }
  }
#pragma unroll
  for (int m = 1; m < 16; m <<= 1) {
#pragma unroll
    for (int q = 0; q < 16; q++) rsum[q] += __shfl_xor(rsum[q], m, 64);
  }

  __syncthreads();
  float* red = (float*)&As[0][0];
  if (fr == 0) {
#pragma unroll
    for (int mi = 0; mi < 4; mi++)
#pragma unroll
      for (int r = 0; r < 4; r++)
        red[wave * 64 + mi * 16 + (lane >> 4) * 4 + r] = rsum[mi * 4 + r];
  }
  __syncthreads();

  if (t < BM) {
    int rl = t;
    int wrow = rl >> 6;
    float S = red[(wrow * 2 + 0) * 64 + (rl & 63)] +
              red[(wrow * 2 + 1) * 64 + (rl & 63)];
    partialS[(size_t)cb * BT + row0 + rl] = S;
  }

  const bool is64 = (*badcnt == 0);
#pragma unroll
  for (int mi = 0; mi < 4; mi++) {
#pragma unroll
    for (int r = 0; r < 4; r++) {
      int grow = row0 + wr * 64 + mi * 16 + ((lane >> 4) << 2) + r;
      long long tv = is64 ? ((const long long*)tgt)[grow]
                          : (long long)((const int*)tgt)[grow];
#pragma unroll
      for (int nj = 0; nj < 4; nj++) {
        int gcol = col0 + wc * 64 + nj * 16 + fr;
        if (tv == (long long)gcol) picked[grow] = acc[mi][nj][r];
      }
    }
  }
}

// ---------------------------------------------------------------------------
// Per-row: S = sum of ncb partials; nll = log(S) - picked.
// ---------------------------------------------------------------------------
__global__ void reduce_rows_kernel(const float* __restrict__ partialS,
                                   const float* __restrict__ picked,
                                   float* __restrict__ nll, int ncb) {
  int r = blockIdx.x * blockDim.x + threadIdx.x;
  if (r >= BT) return;
  float S = 0.f;
  for (int cb = 0; cb < ncb; cb++) S += partialS[(size_t)cb * BT + r];
  nll[r] = logf(fmaxf(S, 1e-37f)) - picked[r];
}

// ---------------------------------------------------------------------------
// Final: loss = sum(nll) / n_non_ignore
// ---------------------------------------------------------------------------
__global__ void reduce_final_kernel(const float* __restrict__ nll,
                                    const void* __restrict__ tgt,
                                    const int* __restrict__ badcnt,
                                    float* __restrict__ out) {
  __shared__ float ssum[256];
  __shared__ int scnt[256];
  int t = threadIdx.x;
  const bool is64 = (*badcnt == 0);
  float s = 0.f;
  int c = 0;
  for (int r = t; r < BT; r += 256) {
    s += nll[r];
    long long tv =
        is64 ? ((const long long*)tgt)[r] : (long long)((const int*)tgt)[r];
    c += (tv != (long long)IGNORE_IDX) ? 1 : 0;
  }
  ssum[t] = s;
  scnt[t] = c;
  __syncthreads();
  for (int o = 128; o > 0; o >>= 1) {
    if (t < o) {
      ssum[t] += ssum[t + o];
      scnt[t] += scnt[t + o];
    }
    __syncthreads();
  }
  if (t == 0) out[0] = ssum[0] / (float)scnt[0];
}

// ---------------------------------------------------------------------------
extern "C" void kernel_launch(void* const* d_in, const int* in_sizes, int n_in,
                              void* d_out, int out_size, void* d_ws,
                              size_t ws_size, hipStream_t stream) {
  const float* x = (const float*)d_in[0];
  const float* w = (const float*)d_in[1];
  const void* tgt = d_in[2];
  float* out = (float*)d_out;

  char* ws = (char*)d_ws;
  // ws layout:
  //   [0, offA)              : partialS (NCB*BT*4 = 4,096,000 B max)
  //   [offA, offA+16)        : badcnt flag (+pad)
  //   [offA+16, +BT*4)       : picked
  //   [.. +BT*4)             : nll
  //   [offX, +BT*HD*2)       : x as bf16
  //   [offW, +VD*HD*2)       : W as bf16
  const size_t offA = (size_t)NCB * BT * 4;
  float* partialS = (float*)ws;
  int* badcnt = (int*)(ws + offA);
  float* picked = (float*)(ws + offA + 16);
  float* nll = (float*)(ws + offA + 16 + (size_t)BT * 4);
  const size_t offX = offA + 16 + 2 * (size_t)BT * 4;
  const size_t offW = offX + (size_t)BT * HD * 2;
  const size_t need = offW + (size_t)VD * HD * 2;

  hipMemsetAsync(ws + offA, 0, 16 + (size_t)BT * 4, stream);

  detect_tgt_kernel<<<8, 256, 0, stream>>>((const long long*)tgt, badcnt);

  if (ws_size >= need) {
    unsigned short* xbf = (unsigned short*)(ws + offX);
    unsigned short* wbf = (unsigned short*)(ws + offW);
    cvt_bf16_kernel<<<2048, 256, 0, stream>>>(x, xbf, BT * HD / 8);
    cvt_bf16_kernel<<<2048, 256, 0, stream>>>(w, wbf, VD * HD / 8);
    gemm_lse_pipe_kernel<<<NRB2 * NCB2, 512, 0, stream>>>(xbf, wbf, tgt,
                                                          badcnt, partialS,
                                                          picked);
    reduce_rows_kernel<<<BT / 256, 256, 0, stream>>>(partialS, picked, nll,
                                                     NCB2);
  } else {
    gemm_lse_kernel<<<NRB * NCB, 256, 0, stream>>>(x, w, tgt, badcnt, partialS,
                                                   picked);
    reduce_rows_kernel<<<BT / 256, 256, 0, stream>>>(partialS, picked, nll,
                                                     NCB);
  }

  reduce_final_kernel<<<1, 256, 0, stream>>>(nll, tgt, badcnt, out);
}

// Round 7
// 777.435 us; speedup vs baseline: 2.0235x; 1.0996x over previous
//
#include <hip/hip_runtime.h>
#include <hip/hip_bf16.h>

// Problem constants (from reference)
#define BT 4096
#define HD 2048
#define VD 32000
#define IGNORE_IDX (-100)

// ---- 256x256 8-phase GEMM geometry (fast path) ----
#define BM2 256
#define BN2 256
#define BK2 64
#define NRB2 (BT / BM2)  // 16
#define NCB2 (VD / BN2)  // 125
#define NKT (HD / BK2)   // 32

// ---- 128x128 fallback geometry (fp32 path) ----
#define BM 128
#define BN 128
#define BKT 32
#define NRB (BT / BM)  // 32
#define NCB (VD / BN)  // 250

using short8 = __attribute__((ext_vector_type(8))) short;
using f32x4 = __attribute__((ext_vector_type(4))) float;

__device__ __forceinline__ unsigned short f2bf(float f) {
  unsigned u = __float_as_uint(f);
  u = (u + 0x7fffu + ((u >> 16) & 1u)) >> 16;
  return (unsigned short)u;
}

// async global->LDS, 16B/lane; LDS dest = wave-uniform base + lane*16.
// offset param MUST stay 0 (R3/R4 NaN root cause) -- all offsets folded
// into the global pointer.
#define GL(SRC, DST)                                         \
  __builtin_amdgcn_global_load_lds(                          \
      (const __attribute__((address_space(1))) void*)(SRC),  \
      (__attribute__((address_space(3))) void*)(DST), 16, 0, 0)

// stage one half-tile (128 rows x 64 K bf16 = 16KB): 2 issues per thread.
// Wave w covers 16-row block i=w; issue j covers k-half j (32 K).
// LDS dest: slot base + (w*2+j)*512 hw  (fragment-order, lane-linear).
#define STG2(GSRC, KOFF, DBASE, SLOT)                 \
  GL((GSRC) + (KOFF), (DBASE) + (SLOT)*8192);         \
  GL((GSRC) + (KOFF) + 32, (DBASE) + (SLOT)*8192 + 512)

// ---------------------------------------------------------------------------
// Detect whether target buffer is int64 or int32 (reads 16KB, safe either way)
// ---------------------------------------------------------------------------
__global__ void detect_tgt_kernel(const long long* __restrict__ t64,
                                  int* __restrict__ badcnt) {
  int i = blockIdx.x * blockDim.x + threadIdx.x;  // 2048 threads
  long long v = t64[i];
  bool valid = (v == (long long)IGNORE_IDX) || (v >= 0 && v < (long long)VD);
  if (!valid) atomicAdd(badcnt, 1);
}

// ---------------------------------------------------------------------------
// fp32 -> bf16 bulk convert
// ---------------------------------------------------------------------------
__global__ void cvt_bf16_kernel(const float* __restrict__ in,
                                unsigned short* __restrict__ out, int n8) {
  int idx = blockIdx.x * blockDim.x + threadIdx.x;
  int stride = gridDim.x * blockDim.x;
  for (int i = idx; i < n8; i += stride) {
    float4 a = ((const float4*)in)[(size_t)2 * i];
    float4 b = ((const float4*)in)[(size_t)2 * i + 1];
    short8 o;
    o[0] = (short)f2bf(a.x);
    o[1] = (short)f2bf(a.y);
    o[2] = (short)f2bf(a.z);
    o[3] = (short)f2bf(a.w);
    o[4] = (short)f2bf(b.x);
    o[5] = (short)f2bf(b.y);
    o[6] = (short)f2bf(b.z);
    o[7] = (short)f2bf(b.w);
    ((short8*)out)[i] = o;
  }
}

// ---------------------------------------------------------------------------
// FAST PATH: 256x256 bf16 GEMM, BK=64, 128KB LDS double-buffer, true 8-phase
// counted-vmcnt schedule (T1+T3+T4+T5), fused with per-(rb,cb) sum(exp) and
// picked-target-logit.
//
// LDS: A = 4 slots x 8192 hw (slot = buf*2 + half; half = 128 rows x 64 K),
//      B same. FRAGMENT-ORDER within a slot: element (row=16i+fr,
//      k=k2*32+kq*8+j) at hw offset (i*2+k2)*512 + (kq*16+fr)*8 -- staging
//      writes are LDS-linear (lane*16B), per-lane GLOBAL source permuted
//      (srow=lane&15, scol=(lane>>4)*8); frag ds_read_b128 is lane-linear:
//      ZERO bank conflicts, no swizzle anywhere.
// 8 waves (2M x 4N); per-wave output 128x64; acc[8][4] f32x4.
// Per K-tile (4 phases): P1{RDA(16)+RDBlo(4) | stage B1(kt+1)}, P2{stage
// A0(kt+2)}, P3{RDBhi(4) | stage A1(kt+2)}, P4{stage B0(kt+2) | vmcnt(6)}.
// All A reads at P1 so the in-buffer A overwrites (P2/P3) are
// barrier-separated from the reads. vmcnt ledger: entering tile kt,
// 6 outstanding {A0,A1,B0 of kt+1}; +2/+2/+2/+2 across P1..P4 -> 14;
// vmcnt(6) at P4 drains exactly tile kt+1's 8 issues.
// ---------------------------------------------------------------------------
__global__ __launch_bounds__(512) void gemm_lse_8ph_kernel(
    const unsigned short* __restrict__ xbf,
    const unsigned short* __restrict__ wbf, const void* __restrict__ tgt,
    const int* __restrict__ badcnt, float* __restrict__ partialS,
    float* __restrict__ picked) {
  __shared__ unsigned short smem[65536];  // 128 KB
  unsigned short* ldsA = smem;            // 4 slots * 8192 hw
  unsigned short* ldsB = smem + 32768;

  const int t = threadIdx.x;

  // zero-init LDS (defensive: any residual ledger bug -> finite-wrong)
  {
    uint4 z = make_uint4(0u, 0u, 0u, 0u);
#pragma unroll
    for (int i = 0; i < 16; i++) ((uint4*)smem)[t + i * 512] = z;
  }
  __syncthreads();

  // T1: bijective XCD swizzle (2000 % 8 == 0), rowblock-fast
  const int bid = blockIdx.x;
  const int cpx = (NRB2 * NCB2) >> 3;  // 250
  const int swz = (bid & 7) * cpx + (bid >> 3);
  const int rb = swz % NRB2;
  const int cb = swz / NRB2;
  const int row0 = rb * BM2;
  const int col0 = cb * BN2;

  const int lane = t & 63;
  const int w = t >> 6;    // 0..7
  const int wm = w >> 2;   // 0..1  (A half)
  const int wn = w & 3;    // 0..3
  const int bh = wn >> 1;  // B half
  const int bn4 = wn & 1;  // 64-col subrange within B half

  const int fr = lane & 15;
  const int kq = lane >> 4;  // 0..3

  // read-side LDS base (fragment-order): lane-linear, conflict-free
  const unsigned short* pA0 = ldsA + (0 * 2 + wm) * 8192 + lane * 8;
  const unsigned short* pA1 = ldsA + (1 * 2 + wm) * 8192 + lane * 8;
  const unsigned short* pB0 =
      ldsB + (0 * 2 + bh) * 8192 + bn4 * 4096 + lane * 8;
  const unsigned short* pB1 =
      ldsB + (1 * 2 + bh) * 8192 + bn4 * 4096 + lane * 8;

  // staging: wave w stages 16-row block i=w of each half-tile; lane
  // l = kq*16+fr sources global (row = w*16 + (l&15), k = (l>>4)*8) and
  // lands at LDS linear l*16B within the (w,j) 512-hw region.
  const int srow = lane & 15;
  const int scol = (lane >> 4) * 8;
  const unsigned short* gA0 =
      xbf + (size_t)(row0 + 0 + w * 16 + srow) * HD + scol;
  const unsigned short* gA1 =
      xbf + (size_t)(row0 + 128 + w * 16 + srow) * HD + scol;
  const unsigned short* gB0 =
      wbf + (size_t)(col0 + 0 + w * 16 + srow) * HD + scol;
  const unsigned short* gB1 =
      wbf + (size_t)(col0 + 128 + w * 16 + srow) * HD + scol;

  unsigned short* dA = ldsA + w * 1024;  // wave's 2KB region within a slot
  unsigned short* dB = ldsB + w * 1024;

  f32x4 acc[8][4];
#pragma unroll
  for (int i = 0; i < 8; i++)
#pragma unroll
    for (int n = 0; n < 4; n++)
#pragma unroll
      for (int q = 0; q < 4; q++) acc[i][n][q] = 0.f;

  short8 aR[8][2], bLo[2][2], bHi[2][2];

#define RDA(P)                                         \
  _Pragma("unroll") for (int i = 0; i < 8; i++)        \
  _Pragma("unroll") for (int k2 = 0; k2 < 2; k2++)     \
      aR[i][k2] = *(const short8*)((P) + i * 1024 + k2 * 512);

#define RDBLO(P)                                       \
  _Pragma("unroll") for (int n = 0; n < 2; n++)        \
  _Pragma("unroll") for (int k2 = 0; k2 < 2; k2++)     \
      bLo[n][k2] = *(const short8*)((P) + n * 1024 + k2 * 512);

#define RDBHI(P)                                       \
  _Pragma("unroll") for (int n = 0; n < 2; n++)        \
  _Pragma("unroll") for (int k2 = 0; k2 < 2; k2++)     \
      bHi[n][k2] = *(const short8*)((P) + (n + 2) * 1024 + k2 * 512);

#define MM16(QM, BR, QN)                                                      \
  _Pragma("unroll") for (int k2 = 0; k2 < 2; k2++)                            \
  _Pragma("unroll") for (int i = 0; i < 4; i++)                               \
  _Pragma("unroll") for (int n = 0; n < 2; n++)                               \
      acc[(QM)*4 + i][(QN)*2 + n] = __builtin_amdgcn_mfma_f32_16x16x32_bf16(  \
          aR[(QM)*4 + i][k2], BR[n][k2], acc[(QM)*4 + i][(QN)*2 + n], 0, 0, 0);

#define BARMFMA(QM, BR, QN)                            \
  __builtin_amdgcn_sched_barrier(0);                   \
  __builtin_amdgcn_s_barrier();                        \
  asm volatile("s_waitcnt lgkmcnt(0)" ::: "memory");   \
  __builtin_amdgcn_sched_barrier(0);                   \
  __builtin_amdgcn_s_setprio(1);                       \
  MM16(QM, BR, QN);                                    \
  __builtin_amdgcn_s_setprio(0);                       \
  __builtin_amdgcn_sched_barrier(0);                   \
  __builtin_amdgcn_s_barrier();                        \
  __builtin_amdgcn_sched_barrier(0);

  // ---- prologue: tile0 fully + A0/A1/B0 of tile1 (14 issues); vmcnt(6) ----
  STG2(gA0, 0, dA, 0);   // A0(0) buf0
  STG2(gA1, 0, dA, 1);   // A1(0)
  STG2(gB0, 0, dB, 0);   // B0(0)
  STG2(gB1, 0, dB, 1);   // B1(0)
  STG2(gA0, 64, dA, 2);  // A0(1) buf1
  STG2(gA1, 64, dA, 3);  // A1(1)
  STG2(gB0, 64, dB, 2);  // B0(1)
  asm volatile("s_waitcnt vmcnt(6)" ::: "memory");  // tile0 landed
  __builtin_amdgcn_s_barrier();

  // ---- main loop: 2 K-tiles (buf0, buf1) per iter, 8 phases ----
  for (int kt = 0; kt + 3 < NKT; kt += 2) {
    // K-tile kt (buf0)
    RDA(pA0);
    RDBLO(pB0);
    STG2(gB1, 64, dB, 3);  // B1(kt+1) -> buf1 half1
    BARMFMA(0, bLo, 0);    // P1
    STG2(gA0, 128, dA, 0);  // A0(kt+2) -> buf0 half0 (reads done at P1 close)
    BARMFMA(1, bLo, 0);    // P2
    RDBHI(pB0);
    STG2(gA1, 128, dA, 1);  // A1(kt+2)
    BARMFMA(1, bHi, 1);    // P3
    STG2(gB0, 128, dB, 0);  // B0(kt+2)
    asm volatile("s_waitcnt vmcnt(6)" ::: "memory");  // tile kt+1 landed
    BARMFMA(0, bHi, 1);    // P4
    // K-tile kt+1 (buf1)
    RDA(pA1);
    RDBLO(pB1);
    STG2(gB1, 128, dB, 1);  // B1(kt+2) -> buf0 half1
    BARMFMA(0, bLo, 0);    // P5
    STG2(gA0, 192, dA, 2);  // A0(kt+3) -> buf1
    BARMFMA(1, bLo, 0);    // P6
    RDBHI(pB1);
    STG2(gA1, 192, dA, 3);  // A1(kt+3)
    BARMFMA(1, bHi, 1);    // P7
    STG2(gB0, 192, dB, 2);  // B0(kt+3)
    asm volatile("s_waitcnt vmcnt(6)" ::: "memory");  // tile kt+2 landed
    BARMFMA(0, bHi, 1);    // P8
    gA0 += 128;  // advance 2 K-tiles (128 hw = 256 B)
    gA1 += 128;
    gB0 += 128;
    gB1 += 128;
  }

  // ---- tail: K-tiles NKT-2 (buf0), NKT-1 (buf1) ----
  {
    RDA(pA0);
    RDBLO(pB0);
    STG2(gB1, 64, dB, 3);  // B1(NKT-1)
    BARMFMA(0, bLo, 0);
    BARMFMA(1, bLo, 0);
    RDBHI(pB0);
    BARMFMA(1, bHi, 1);
    asm volatile("s_waitcnt vmcnt(0)" ::: "memory");  // tile NKT-1 landed
    BARMFMA(0, bHi, 1);
    RDA(pA1);
    RDBLO(pB1);
    BARMFMA(0, bLo, 0);
    BARMFMA(1, bLo, 0);
    RDBHI(pB1);
    BARMFMA(1, bHi, 1);
    BARMFMA(0, bHi, 1);
  }

  // ---- epilogue: per-row sum(exp) over this block's 256 cols ----
  // C/D layout: col = col0 + wn*64 + n*16 + fr ;
  //             row = row0 + wm*128 + i*16 + kq*4 + q
  __syncthreads();
  float* red = (float*)smem;  // [256 rows][4 wn] floats = 4KB
#pragma unroll
  for (int i = 0; i < 8; i++) {
#pragma unroll
    for (int q = 0; q < 4; q++) {
      float s = 0.f;
#pragma unroll
      for (int n = 0; n < 4; n++) s += expf(acc[i][n][q]);
#pragma unroll
      for (int m = 1; m < 16; m <<= 1) s += __shfl_xor(s, m, 64);
      if (fr == 0) red[(wm * 128 + i * 16 + kq * 4 + q) * 4 + wn] = s;
    }
  }
  __syncthreads();
  if (t < 256) {
    float S = red[t * 4 + 0] + red[t * 4 + 1] + red[t * 4 + 2] + red[t * 4 + 3];
    partialS[(size_t)cb * BT + row0 + t] = S;
  }

  // ---- picked target logit (single writer per row across the grid) ----
  const bool is64 = (*badcnt == 0);
#pragma unroll
  for (int i = 0; i < 8; i++) {
#pragma unroll
    for (int q = 0; q < 4; q++) {
      int grow = row0 + wm * 128 + i * 16 + kq * 4 + q;
      long long tv = is64 ? ((const long long*)tgt)[grow]
                          : (long long)((const int*)tgt)[grow];
#pragma unroll
      for (int n = 0; n < 4; n++) {
        int gcol = col0 + wn * 64 + n * 16 + fr;
        if (tv == (long long)gcol) picked[grow] = acc[i][n][q];
      }
    }
  }
#undef RDA
#undef RDBLO
#undef RDBHI
#undef MM16
#undef BARMFMA
}

// ---------------------------------------------------------------------------
// FALLBACK PATH (ws too small): fp32 inputs with on-the-fly cvt
// ---------------------------------------------------------------------------
__global__ __launch_bounds__(256) void gemm_lse_kernel(
    const float* __restrict__ x, const float* __restrict__ w,
    const void* __restrict__ tgt, const int* __restrict__ badcnt,
    float* __restrict__ partialS, float* __restrict__ picked) {
  __shared__ unsigned short As[BM][BKT];
  __shared__ unsigned short Bs[BN][BKT];

  const int bid = blockIdx.x;
  const int rb = bid % NRB;
  const int cb = bid / NRB;
  const int row0 = rb * BM;
  const int col0 = cb * BN;
  const int t = threadIdx.x;
  const int lane = t & 63;
  const int wave = t >> 6;
  const int wr = wave >> 1;
  const int wc = wave & 1;

  const int srow = t >> 3;
  const int scol = (t & 7) * 4;

  const float* xA = x + (size_t)row0 * HD;
  const float* wB = w + (size_t)col0 * HD;

  f32x4 acc[4][4];
#pragma unroll
  for (int i = 0; i < 4; i++)
#pragma unroll
    for (int j = 0; j < 4; j++)
#pragma unroll
      for (int q = 0; q < 4; q++) acc[i][j][q] = 0.f;

  float4 ra[4], rbv[4];

#define STAGE_LOAD(k0)                                                        \
  {                                                                           \
    _Pragma("unroll") for (int j = 0; j < 4; j++) {                           \
      ra[j] = *(const float4*)(xA + (size_t)(srow + j * 32) * HD + (k0) + scol); \
      rbv[j] = *(const float4*)(wB + (size_t)(srow + j * 32) * HD + (k0) + scol); \
    }                                                                         \
  }
#define STAGE_WRITE()                                                         \
  {                                                                           \
    _Pragma("unroll") for (int j = 0; j < 4; j++) {                           \
      ushort4 pa = make_ushort4(f2bf(ra[j].x), f2bf(ra[j].y), f2bf(ra[j].z),  \
                                f2bf(ra[j].w));                               \
      ushort4 pb = make_ushort4(f2bf(rbv[j].x), f2bf(rbv[j].y),               \
                                f2bf(rbv[j].z), f2bf(rbv[j].w));              \
      *(ushort4*)&As[srow + j * 32][scol] = pa;                               \
      *(ushort4*)&Bs[srow + j * 32][scol] = pb;                               \
    }                                                                         \
  }

  const int ks = (lane >> 4) * 8;
  const int fr = lane & 15;

  STAGE_LOAD(0);
  STAGE_WRITE();
  __syncthreads();

  for (int k0 = 0; k0 < HD; k0 += BKT) {
    const bool notlast = (k0 + BKT < HD);
    if (notlast) STAGE_LOAD(k0 + BKT);

    short8 af[4], bfv[4];
#pragma unroll
    for (int i = 0; i < 4; i++) {
      af[i] = *(const short8*)&As[wr * 64 + i * 16 + fr][ks];
      bfv[i] = *(const short8*)&Bs[wc * 64 + i * 16 + fr][ks];
    }
#pragma unroll
    for (int i = 0; i < 4; i++)
#pragma unroll
      for (int j = 0; j < 4; j++)
        acc[i][j] = __builtin_amdgcn_mfma_f32_16x16x32_bf16(af[i], bfv[j],
                                                            acc[i][j], 0, 0, 0);

    __syncthreads();
    if (notlast) STAGE_WRITE();
    __syncthreads();
  }
#undef STAGE_LOAD
#undef STAGE_WRITE

  float rsum[16];
#pragma unroll
  for (int mi = 0; mi < 4; mi++) {
#pragma unroll
    for (int r = 0; r < 4; r++) {
      float s = 0.f;
#pragma unroll
      for (int nj = 0; nj < 4; nj++) s += expf(acc[mi][nj][r]);
      rsum[mi * 4 + r] = s;
    }
  }
#pragma unroll
  for (int m = 1; m < 16; m <<= 1) {
#pragma unroll
    for (int q = 0; q < 16; q++) rsum[q] += __shfl_xor(rsum[q], m, 64);
  }

  __syncthreads();
  float* red = (float*)&As[0][0];
  if (fr == 0) {
#pragma unroll
    for (int mi = 0; mi < 4; mi++)
#pragma unroll
      for (int r = 0; r < 4; r++)
        red[wave * 64 + mi * 16 + (lane >> 4) * 4 + r] = rsum[mi * 4 + r];
  }
  __syncthreads();

  if (t < BM) {
    int rl = t;
    int wrow = rl >> 6;
    float S = red[(wrow * 2 + 0) * 64 + (rl & 63)] +
              red[(wrow * 2 + 1) * 64 + (rl & 63)];
    partialS[(size_t)cb * BT + row0 + rl] = S;
  }

  const bool is64 = (*badcnt == 0);
#pragma unroll
  for (int mi = 0; mi < 4; mi++) {
#pragma unroll
    for (int r = 0; r < 4; r++) {
      int grow = row0 + wr * 64 + mi * 16 + ((lane >> 4) << 2) + r;
      long long tv = is64 ? ((const long long*)tgt)[grow]
                          : (long long)((const int*)tgt)[grow];
#pragma unroll
      for (int nj = 0; nj < 4; nj++) {
        int gcol = col0 + wc * 64 + nj * 16 + fr;
        if (tv == (long long)gcol) picked[grow] = acc[mi][nj][r];
      }
    }
  }
}

// ---------------------------------------------------------------------------
// Per-row: S = sum of ncb partials; nll = log(S) - picked.
// ---------------------------------------------------------------------------
__global__ void reduce_rows_kernel(const float* __restrict__ partialS,
                                   const float* __restrict__ picked,
                                   float* __restrict__ nll, int ncb) {
  int r = blockIdx.x * blockDim.x + threadIdx.x;
  if (r >= BT) return;
  float S = 0.f;
  for (int cb = 0; cb < ncb; cb++) S += partialS[(size_t)cb * BT + r];
  nll[r] = logf(fmaxf(S, 1e-37f)) - picked[r];
}

// ---------------------------------------------------------------------------
// Final: loss = sum(nll) / n_non_ignore
// ---------------------------------------------------------------------------
__global__ void reduce_final_kernel(const float* __restrict__ nll,
                                    const void* __restrict__ tgt,
                                    const int* __restrict__ badcnt,
                                    float* __restrict__ out) {
  __shared__ float ssum[256];
  __shared__ int scnt[256];
  int t = threadIdx.x;
  const bool is64 = (*badcnt == 0);
  float s = 0.f;
  int c = 0;
  for (int r = t; r < BT; r += 256) {
    s += nll[r];
    long long tv =
        is64 ? ((const long long*)tgt)[r] : (long long)((const int*)tgt)[r];
    c += (tv != (long long)IGNORE_IDX) ? 1 : 0;
  }
  ssum[t] = s;
  scnt[t] = c;
  __syncthreads();
  for (int o = 128; o > 0; o >>= 1) {
    if (t < o) {
      ssum[t] += ssum[t + o];
      scnt[t] += scnt[t + o];
    }
    __syncthreads();
  }
  if (t == 0) out[0] = ssum[0] / (float)scnt[0];
}

// ---------------------------------------------------------------------------
extern "C" void kernel_launch(void* const* d_in, const int* in_sizes, int n_in,
                              void* d_out, int out_size, void* d_ws,
                              size_t ws_size, hipStream_t stream) {
  const float* x = (const float*)d_in[0];
  const float* w = (const float*)d_in[1];
  const void* tgt = d_in[2];
  float* out = (float*)d_out;

  char* ws = (char*)d_ws;
  // ws layout:
  //   [0, offA)              : partialS (NCB*BT*4 = 4,096,000 B max)
  //   [offA, offA+16)        : badcnt flag (+pad)
  //   [offA+16, +BT*4)       : picked
  //   [.. +BT*4)             : nll
  //   [offX, +BT*HD*2)       : x as bf16
  //   [offW, +VD*HD*2)       : W as bf16
  const size_t offA = (size_t)NCB * BT * 4;
  float* partialS = (float*)ws;
  int* badcnt = (int*)(ws + offA);
  float* picked = (float*)(ws + offA + 16);
  float* nll = (float*)(ws + offA + 16 + (size_t)BT * 4);
  const size_t offX = offA + 16 + 2 * (size_t)BT * 4;
  const size_t offW = offX + (size_t)BT * HD * 2;
  const size_t need = offW + (size_t)VD * HD * 2;

  hipMemsetAsync(ws + offA, 0, 16 + (size_t)BT * 4, stream);

  detect_tgt_kernel<<<8, 256, 0, stream>>>((const long long*)tgt, badcnt);

  if (ws_size >= need) {
    unsigned short* xbf = (unsigned short*)(ws + offX);
    unsigned short* wbf = (unsigned short*)(ws + offW);
    cvt_bf16_kernel<<<2048, 256, 0, stream>>>(x, xbf, BT * HD / 8);
    cvt_bf16_kernel<<<2048, 256, 0, stream>>>(w, wbf, VD * HD / 8);
    gemm_lse_8ph_kernel<<<NRB2 * NCB2, 512, 0, stream>>>(xbf, wbf, tgt, badcnt,
                                                         partialS, picked);
    reduce_rows_kernel<<<BT / 256, 256, 0, stream>>>(partialS, picked, nll,
                                                     NCB2);
  } else {
    gemm_lse_kernel<<<NRB * NCB, 256, 0, stream>>>(x, w, tgt, badcnt, partialS,
                                                   picked);
    reduce_rows_kernel<<<BT / 256, 256, 0, stream>>>(partialS, picked, nll,
                                                     NCB);
  }

  reduce_final_kernel<<<1, 256, 0, stream>>>(nll, tgt, badcnt, out);
}